// Round 8
// baseline (1533.099 us; speedup 1.0000x reference)
//
#include <hip/hip_runtime.h>

// SGC: h = relu(x @ W^T + b); 3x { h = segment_sum(h[src]*w, dst) }
// Round 8 == round 6/7 resubmitted verbatim (infra failures; design unmeasured).
// Design: edges grouped by 64-node dst-bucket; one WG per bucket accumulates
// into padded LDS [64][33] via unsafeAtomicAdd (-> ds_add_f32); uniform
// unrolled 32-edges/iter loop; one coalesced row write per node.
constexpr int N_NODES_C = 100000;
constexpr int N_EDGES_C = 1600000;
constexpr int IN_DIM_C  = 128;
constexpr int EMB       = 32;

constexpr int NPB      = 64;                              // nodes per bucket
constexpr int NB       = (N_NODES_C + NPB - 1) / NPB;     // 1563 buckets
constexpr int SMSTRIDE = 33;                              // LDS row pad (bank spread)
constexpr int SCAN_PER = (NB + 255) / 256;                // 7 elems per scan thread

// ---------------------------------------------------------------------------
// h0 = relu(x W^T + b). One thread per row; W (16 KB) via wave-uniform loads.
// ---------------------------------------------------------------------------
__global__ __launch_bounds__(256) void linear_relu_kernel(
    const float* __restrict__ x, const float* __restrict__ W,
    const float* __restrict__ b, float* __restrict__ h, int n)
{
    int row = blockIdx.x * 256 + threadIdx.x;
    if (row >= n) return;
    const float4* __restrict__ xr =
        reinterpret_cast<const float4*>(x + (size_t)row * IN_DIM_C);
    const float4* __restrict__ W4 = reinterpret_cast<const float4*>(W);

    float acc[EMB];
#pragma unroll
    for (int e = 0; e < EMB; ++e) acc[e] = 0.f;

#pragma unroll 2
    for (int k4 = 0; k4 < IN_DIM_C / 4; ++k4) {
        float4 xv = xr[k4];
#pragma unroll
        for (int e = 0; e < EMB; ++e) {
            float4 wv = W4[e * (IN_DIM_C / 4) + k4];
            acc[e] = fmaf(xv.x, wv.x,
                     fmaf(xv.y, wv.y,
                     fmaf(xv.z, wv.z,
                     fmaf(xv.w, wv.w, acc[e]))));
        }
    }

    float* __restrict__ out = h + (size_t)row * EMB;
#pragma unroll
    for (int e = 0; e < EMB; ++e) {
        float v = acc[e] + b[e];
        out[e] = v > 0.f ? v : 0.f;
    }
}

// ---------------------------------------------------------------------------
// Bucket histogram: bcnt[dst>>6]++ over all edges.
// ---------------------------------------------------------------------------
__global__ __launch_bounds__(256) void bucket_hist_kernel(
    const int* __restrict__ dst, int* __restrict__ bcnt)
{
    int e = blockIdx.x * 256 + threadIdx.x;
    if (e < N_EDGES_C) atomicAdd(&bcnt[dst[e] >> 6], 1);
}

// ---------------------------------------------------------------------------
// Single-WG exclusive scan of the 1563 bucket counts -> boff; zero bcur.
// ---------------------------------------------------------------------------
__global__ __launch_bounds__(256) void scan_buckets_kernel(
    const int* __restrict__ bcnt, int* __restrict__ boff, int* __restrict__ bcur)
{
    int t = threadIdx.x;
    int base = t * SCAN_PER;
    int v[SCAN_PER];
    int s = 0;
#pragma unroll
    for (int i = 0; i < SCAN_PER; ++i) {
        int x = (base + i < NB) ? bcnt[base + i] : 0;
        v[i] = x; s += x;
    }
    // inclusive scan of per-thread sums across 256 threads
    int lane = t & 63, wid = t >> 6;
    int inc = s;
#pragma unroll
    for (int o = 1; o < 64; o <<= 1) {
        int u = __shfl_up(inc, o, 64);
        if (lane >= o) inc += u;
    }
    __shared__ int wtot[4];
    if (lane == 63) wtot[wid] = inc;
    __syncthreads();
    int wbase = 0;
    for (int i = 0; i < wid; ++i) wbase += wtot[i];
    int run = wbase + inc - s;   // exclusive prefix for this thread's chunk
#pragma unroll
    for (int i = 0; i < SCAN_PER; ++i) {
        if (base + i < NB) { boff[base + i] = run; bcur[base + i] = 0; }
        run += v[i];
    }
    if (t == 255) boff[NB] = run;   // == N_EDGES_C
}

// ---------------------------------------------------------------------------
// Fill: append each edge to its bucket region. rec = {src | dlow<<17, w}.
// (Random 8B scatter -> ~8x HBM write amplification; known cost ~100us;
// candidate for next round once hops are validated.)
// ---------------------------------------------------------------------------
__global__ __launch_bounds__(256) void fill_kernel(
    const int* __restrict__ src, const int* __restrict__ dst,
    const float* __restrict__ w, const int* __restrict__ boff,
    int* __restrict__ bcur, int2* __restrict__ recs)
{
    int e = blockIdx.x * 256 + threadIdx.x;
    if (e >= N_EDGES_C) return;
    int d   = dst[e];
    int bkt = d >> 6;
    int pos = boff[bkt] + atomicAdd(&bcur[bkt], 1);
    recs[pos] = make_int2(src[e] | ((d & 63) << 17), __float_as_int(w[e]));
}

// ---------------------------------------------------------------------------
// Hop: one WG per 64-node bucket. LDS accumulators [64][33] (padded).
// 8 lanes per edge (one float4 each); 32 edges/WG/iter, unrolled 4x.
// ---------------------------------------------------------------------------
__global__ __launch_bounds__(256) void hop_bucket_kernel(
    const float* __restrict__ h_in, const int* __restrict__ boff,
    const int2* __restrict__ recs, float* __restrict__ h_out)
{
    __shared__ float sm[NPB * SMSTRIDE];
    int tid = threadIdx.x;
    for (int i = tid; i < NPB * SMSTRIDE; i += 256) sm[i] = 0.f;
    __syncthreads();

    int b   = blockIdx.x;
    int beg = boff[b], end = boff[b + 1];
    int q   = tid & 7;        // float4 slot within the 32-dim row
    int eo  = tid >> 3;       // edge slot within group of 32

    int cnt      = end - beg;
    int full_end = beg + (cnt & ~127);

    int base = beg;
    for (; base < full_end; base += 128) {
        int j = base + eo;
        int2 ra = recs[j];
        int2 rb = recs[j + 32];
        int2 rc = recs[j + 64];
        int2 rd = recs[j + 96];
        float4 va = reinterpret_cast<const float4*>(
                        h_in + (size_t)(ra.x & 0x1FFFF) * EMB)[q];
        float4 vb = reinterpret_cast<const float4*>(
                        h_in + (size_t)(rb.x & 0x1FFFF) * EMB)[q];
        float4 vc = reinterpret_cast<const float4*>(
                        h_in + (size_t)(rc.x & 0x1FFFF) * EMB)[q];
        float4 vd = reinterpret_cast<const float4*>(
                        h_in + (size_t)(rd.x & 0x1FFFF) * EMB)[q];

        {
            float wt = __int_as_float(ra.y);
            float* srow = &sm[(ra.x >> 17) * SMSTRIDE + q * 4];
            unsafeAtomicAdd(srow + 0, va.x * wt);
            unsafeAtomicAdd(srow + 1, va.y * wt);
            unsafeAtomicAdd(srow + 2, va.z * wt);
            unsafeAtomicAdd(srow + 3, va.w * wt);
        }
        {
            float wt = __int_as_float(rb.y);
            float* srow = &sm[(rb.x >> 17) * SMSTRIDE + q * 4];
            unsafeAtomicAdd(srow + 0, vb.x * wt);
            unsafeAtomicAdd(srow + 1, vb.y * wt);
            unsafeAtomicAdd(srow + 2, vb.z * wt);
            unsafeAtomicAdd(srow + 3, vb.w * wt);
        }
        {
            float wt = __int_as_float(rc.y);
            float* srow = &sm[(rc.x >> 17) * SMSTRIDE + q * 4];
            unsafeAtomicAdd(srow + 0, vc.x * wt);
            unsafeAtomicAdd(srow + 1, vc.y * wt);
            unsafeAtomicAdd(srow + 2, vc.z * wt);
            unsafeAtomicAdd(srow + 3, vc.w * wt);
        }
        {
            float wt = __int_as_float(rd.y);
            float* srow = &sm[(rd.x >> 17) * SMSTRIDE + q * 4];
            unsafeAtomicAdd(srow + 0, vd.x * wt);
            unsafeAtomicAdd(srow + 1, vd.y * wt);
            unsafeAtomicAdd(srow + 2, vd.z * wt);
            unsafeAtomicAdd(srow + 3, vd.w * wt);
        }
    }
    // tail (< 128 edges)
    for (int j = base + eo; j < end; j += 32) {
        int2  r  = recs[j];
        float wt = __int_as_float(r.y);
        float4 v = reinterpret_cast<const float4*>(
                       h_in + (size_t)(r.x & 0x1FFFF) * EMB)[q];
        float* srow = &sm[(r.x >> 17) * SMSTRIDE + q * 4];
        unsafeAtomicAdd(srow + 0, v.x * wt);
        unsafeAtomicAdd(srow + 1, v.y * wt);
        unsafeAtomicAdd(srow + 2, v.z * wt);
        unsafeAtomicAdd(srow + 3, v.w * wt);
    }

    __syncthreads();
    // write out 64 rows x 32 floats, fully coalesced
    int node0 = b * NPB;
    for (int i = tid; i < NPB * 8; i += 256) {
        int r = i >> 3, c = i & 7;
        int node = node0 + r;
        if (node < N_NODES_C) {
            const float* s = &sm[r * SMSTRIDE + c * 4];
            float4 v = make_float4(s[0], s[1], s[2], s[3]);
            *reinterpret_cast<float4*>(h_out + (size_t)node * EMB + c * 4) = v;
        }
    }
}

extern "C" void kernel_launch(void* const* d_in, const int* in_sizes, int n_in,
                              void* d_out, int out_size, void* d_ws, size_t ws_size,
                              hipStream_t stream) {
    const float* x   = (const float*)d_in[0];
    const float* W   = (const float*)d_in[1];
    const float* b   = (const float*)d_in[2];
    const float* w   = (const float*)d_in[3];
    const int*   src = (const int*)d_in[4];
    const int*   dst = (const int*)d_in[5];
    // d_in[6] is k (== 3, fixed by setup); hardcoded.

    float* out = (float*)d_out;

    char* ws = (char*)d_ws;
    size_t o = 0;
    auto alloc = [&](size_t bytes) {
        char* p = ws + o;
        o += (bytes + 255) & ~(size_t)255;
        return p;
    };
    float* h0   = (float*)alloc((size_t)N_NODES_C * EMB * sizeof(float)); // 12.8 MB
    int*   bcnt = (int*)  alloc((size_t)NB * sizeof(int));
    int*   boff = (int*)  alloc((size_t)(NB + 1) * sizeof(int));
    int*   bcur = (int*)  alloc((size_t)NB * sizeof(int));
    int2*  recs = (int2*) alloc((size_t)N_EDGES_C * sizeof(int2));        // 12.8 MB

    const int EB = (N_EDGES_C + 255) / 256;   // 6250 edge blocks

    // --- bucket CSR build ---
    hipMemsetAsync(bcnt, 0, (size_t)NB * sizeof(int), stream);
    bucket_hist_kernel<<<EB, 256, 0, stream>>>(dst, bcnt);
    scan_buckets_kernel<<<1, 256, 0, stream>>>(bcnt, boff, bcur);
    fill_kernel<<<EB, 256, 0, stream>>>(src, dst, w, boff, bcur, recs);

    // --- h0 = relu(x W^T + b) ---
    linear_relu_kernel<<<(N_NODES_C + 255) / 256, 256, 0, stream>>>(
        x, W, b, h0, N_NODES_C);

    // --- 3 bucket-hops: h0 -> out -> h0 -> out ---
    hop_bucket_kernel<<<NB, 256, 0, stream>>>(h0, boff, recs, out);
    hop_bucket_kernel<<<NB, 256, 0, stream>>>(out, boff, recs, h0);
    hop_bucket_kernel<<<NB, 256, 0, stream>>>(h0, boff, recs, out);
}

// Round 12
// 439.144 us; speedup vs baseline: 3.4911x; 3.4911x over previous
//
#include <hip/hip_runtime.h>

// SGC: h = relu(x @ W^T + b); 3x { h = segment_sum(h[src]*w, dst) }
// Round 12 == round 9/10/11 resubmitted verbatim (repeated infra failures;
// design still unmeasured). Register-accumulating CSR hops (round-4 proven
// ~85us/hop) + two-stage low-amplification CSR build:
//   A) colored bucket fill: (bucket=dst>>6, color=blockIdx&7) runs -> ~1KB
//      contiguous appends per color => ~1x write amp (round-4 fill was 8x,
//      101MB/105us; round-8 LDS-atomic hops were 301us -> rejected).
//   B) per-bucket LDS counting sort by dst&63 -> exact per-node runs +
//      node offsets, all coalesced IO.
constexpr int N_NODES_C = 100000;
constexpr int N_EDGES_C = 1600000;
constexpr int IN_DIM_C  = 128;
constexpr int EMB       = 32;

constexpr int NPB   = 64;                            // nodes per bucket
constexpr int NB    = (N_NODES_C + NPB - 1) / NPB;   // 1563 buckets
constexpr int NCOL  = 8;                             // colors (XCD proxy)
constexpr int NCNT  = NB * NCOL;                     // 12504 counters
constexpr int SCAN_PER = (NCNT + 255) / 256;         // 49 per scan thread

// ---------------------------------------------------------------------------
// h0 = relu(x W^T + b). One thread per row; W (16 KB) via wave-uniform loads.
// ---------------------------------------------------------------------------
__global__ __launch_bounds__(256) void linear_relu_kernel(
    const float* __restrict__ x, const float* __restrict__ W,
    const float* __restrict__ b, float* __restrict__ h, int n)
{
    int row = blockIdx.x * 256 + threadIdx.x;
    if (row >= n) return;
    const float4* __restrict__ xr =
        reinterpret_cast<const float4*>(x + (size_t)row * IN_DIM_C);
    const float4* __restrict__ W4 = reinterpret_cast<const float4*>(W);

    float acc[EMB];
#pragma unroll
    for (int e = 0; e < EMB; ++e) acc[e] = 0.f;

#pragma unroll 2
    for (int k4 = 0; k4 < IN_DIM_C / 4; ++k4) {
        float4 xv = xr[k4];
#pragma unroll
        for (int e = 0; e < EMB; ++e) {
            float4 wv = W4[e * (IN_DIM_C / 4) + k4];
            acc[e] = fmaf(xv.x, wv.x,
                     fmaf(xv.y, wv.y,
                     fmaf(xv.z, wv.z,
                     fmaf(xv.w, wv.w, acc[e]))));
        }
    }

    float* __restrict__ out = h + (size_t)row * EMB;
#pragma unroll
    for (int e = 0; e < EMB; ++e) {
        float v = acc[e] + b[e];
        out[e] = v > 0.f ? v : 0.f;
    }
}

// ---------------------------------------------------------------------------
// Hist over (bucket,color): cnt8[(dst>>6)*8 + (blockIdx&7)]++.
// color is a pure function of the block index, so the fill pass reproduces
// the exact same edge->counter mapping.
// ---------------------------------------------------------------------------
__global__ __launch_bounds__(256) void hist8_kernel(
    const int* __restrict__ dst, int* __restrict__ cnt8)
{
    int e = blockIdx.x * 256 + threadIdx.x;
    if (e < N_EDGES_C)
        atomicAdd(&cnt8[(dst[e] >> 6) * NCOL + (blockIdx.x & 7)], 1);
}

// ---------------------------------------------------------------------------
// Single-WG exclusive scan of 12504 counters -> boff8; zero cur8.
// Layout bucket-major, color-minor: a bucket's 8 color runs are contiguous,
// so bucket b's full range is [boff8[b*8], boff8[(b+1)*8]).
// ---------------------------------------------------------------------------
__global__ __launch_bounds__(256) void scan12k_kernel(
    const int* __restrict__ cnt8, int* __restrict__ boff8, int* __restrict__ cur8)
{
    int t = threadIdx.x;
    int base = t * SCAN_PER;
    int v[SCAN_PER];
    int s = 0;
#pragma unroll
    for (int i = 0; i < SCAN_PER; ++i) {
        int x = (base + i < NCNT) ? cnt8[base + i] : 0;
        v[i] = x; s += x;
    }
    int lane = t & 63, wid = t >> 6;
    int inc = s;
#pragma unroll
    for (int o = 1; o < 64; o <<= 1) {
        int u = __shfl_up(inc, o, 64);
        if (lane >= o) inc += u;
    }
    __shared__ int wtot[4];
    if (lane == 63) wtot[wid] = inc;
    __syncthreads();
    int wbase = 0;
    for (int i = 0; i < wid; ++i) wbase += wtot[i];
    int run = wbase + inc - s;
#pragma unroll
    for (int i = 0; i < SCAN_PER; ++i) {
        if (base + i < NCNT) { boff8[base + i] = run; cur8[base + i] = 0; }
        run += v[i];
    }
    if (t == 255) boff8[NCNT] = run;   // == N_EDGES_C
}

// ---------------------------------------------------------------------------
// Colored fill: append {src | dlow<<17, w} to the (bucket,color) run.
// Each run is appended only by blocks of one color => full-line writes.
// ---------------------------------------------------------------------------
__global__ __launch_bounds__(256) void cfill_kernel(
    const int* __restrict__ src, const int* __restrict__ dst,
    const float* __restrict__ w, const int* __restrict__ boff8,
    int* __restrict__ cur8, int2* __restrict__ recs)
{
    int e = blockIdx.x * 256 + threadIdx.x;
    if (e >= N_EDGES_C) return;
    int d   = dst[e];
    int idx = (d >> 6) * NCOL + (blockIdx.x & 7);
    int pos = boff8[idx] + atomicAdd(&cur8[idx], 1);
    recs[pos] = make_int2(src[e] | ((d & 63) << 17), __float_as_int(w[e]));
}

// ---------------------------------------------------------------------------
// Per-bucket counting sort by dlow -> recs2 (node-contiguous) + nodeoff.
// One WG per bucket; WG-private 8KB output region => no write amplification.
// ---------------------------------------------------------------------------
__global__ __launch_bounds__(256) void sort_kernel(
    const int2* __restrict__ recs, const int* __restrict__ boff8,
    int2* __restrict__ recs2, int* __restrict__ nodeoff)
{
    __shared__ int hist[NPB];
    __shared__ int pfx[NPB];
    __shared__ int cur[NPB];
    int t = threadIdx.x;
    int b = blockIdx.x;
    if (t < NPB) { hist[t] = 0; cur[t] = 0; }
    __syncthreads();

    int beg = boff8[b * NCOL];
    int end = boff8[(b + 1) * NCOL];

    for (int j = beg + t; j < end; j += 256)
        atomicAdd(&hist[(recs[j].x >> 17) & 63], 1);
    __syncthreads();

    if (t == 0) {
        int run = 0;
        for (int i = 0; i < NPB; ++i) { pfx[i] = run; run += hist[i]; }
    }
    __syncthreads();

    // absolute per-node offsets (node 100000 gets E via bucket 1562, i=32)
    if (t < NPB) {
        int node = b * NPB + t;
        if (node <= N_NODES_C) nodeoff[node] = beg + pfx[t];
    }

    for (int j = beg + t; j < end; j += 256) {
        int2 r = recs[j];
        int dlow = (r.x >> 17) & 63;
        int pos  = beg + pfx[dlow] + atomicAdd(&cur[dlow], 1);
        recs2[pos] = make_int2(r.x & 0x1FFFF, r.y);
    }
}

// ---------------------------------------------------------------------------
// Hop (pull, register accumulation): 8 lanes per node, one float4 per lane.
// Unroll-4 for memory-level parallelism. No atomics anywhere.
// ---------------------------------------------------------------------------
__global__ __launch_bounds__(256) void hop_csr_kernel(
    const float* __restrict__ h_in, const int* __restrict__ nodeoff,
    const int2* __restrict__ recs2, float* __restrict__ h_out)
{
    int tid = blockIdx.x * 256 + threadIdx.x;
    int node = tid >> 3;
    int q    = tid & 7;
    if (node >= N_NODES_C) return;

    int beg = nodeoff[node], end = nodeoff[node + 1];
    float4 acc = make_float4(0.f, 0.f, 0.f, 0.f);
    int j = beg;
    for (; j + 4 <= end; j += 4) {
        int2 ep0 = recs2[j + 0];
        int2 ep1 = recs2[j + 1];
        int2 ep2 = recs2[j + 2];
        int2 ep3 = recs2[j + 3];
        float4 h0 = *reinterpret_cast<const float4*>(h_in + (size_t)ep0.x * EMB + q * 4);
        float4 h1 = *reinterpret_cast<const float4*>(h_in + (size_t)ep1.x * EMB + q * 4);
        float4 h2 = *reinterpret_cast<const float4*>(h_in + (size_t)ep2.x * EMB + q * 4);
        float4 h3 = *reinterpret_cast<const float4*>(h_in + (size_t)ep3.x * EMB + q * 4);
        float w0 = __int_as_float(ep0.y), w1 = __int_as_float(ep1.y);
        float w2 = __int_as_float(ep2.y), w3 = __int_as_float(ep3.y);
        acc.x = fmaf(h0.x, w0, acc.x); acc.y = fmaf(h0.y, w0, acc.y);
        acc.z = fmaf(h0.z, w0, acc.z); acc.w = fmaf(h0.w, w0, acc.w);
        acc.x = fmaf(h1.x, w1, acc.x); acc.y = fmaf(h1.y, w1, acc.y);
        acc.z = fmaf(h1.z, w1, acc.z); acc.w = fmaf(h1.w, w1, acc.w);
        acc.x = fmaf(h2.x, w2, acc.x); acc.y = fmaf(h2.y, w2, acc.y);
        acc.z = fmaf(h2.z, w2, acc.z); acc.w = fmaf(h2.w, w2, acc.w);
        acc.x = fmaf(h3.x, w3, acc.x); acc.y = fmaf(h3.y, w3, acc.y);
        acc.z = fmaf(h3.z, w3, acc.z); acc.w = fmaf(h3.w, w3, acc.w);
    }
    for (; j < end; ++j) {
        int2  ep = recs2[j];
        float wt = __int_as_float(ep.y);
        float4 hv = *reinterpret_cast<const float4*>(h_in + (size_t)ep.x * EMB + q * 4);
        acc.x = fmaf(hv.x, wt, acc.x);
        acc.y = fmaf(hv.y, wt, acc.y);
        acc.z = fmaf(hv.z, wt, acc.z);
        acc.w = fmaf(hv.w, wt, acc.w);
    }
    *reinterpret_cast<float4*>(h_out + (size_t)node * EMB + q * 4) = acc;
}

extern "C" void kernel_launch(void* const* d_in, const int* in_sizes, int n_in,
                              void* d_out, int out_size, void* d_ws, size_t ws_size,
                              hipStream_t stream) {
    const float* x   = (const float*)d_in[0];
    const float* W   = (const float*)d_in[1];
    const float* b   = (const float*)d_in[2];
    const float* w   = (const float*)d_in[3];
    const int*   src = (const int*)d_in[4];
    const int*   dst = (const int*)d_in[5];
    // d_in[6] is k (== 3, fixed by setup); hardcoded.

    float* out = (float*)d_out;

    char* ws = (char*)d_ws;
    size_t o = 0;
    auto alloc = [&](size_t bytes) {
        char* p = ws + o;
        o += (bytes + 255) & ~(size_t)255;
        return p;
    };
    float* h0      = (float*)alloc((size_t)N_NODES_C * EMB * sizeof(float)); // 12.8 MB
    int*   cnt8    = (int*)  alloc((size_t)NCNT * sizeof(int));              // 50 KB
    int*   boff8   = (int*)  alloc((size_t)(NCNT + 1) * sizeof(int));        // 50 KB
    int*   cur8    = (int*)  alloc((size_t)NCNT * sizeof(int));              // 50 KB
    int*   nodeoff = (int*)  alloc((size_t)(N_NODES_C + 1) * sizeof(int));   // 400 KB
    int2*  recs    = (int2*) alloc((size_t)N_EDGES_C * sizeof(int2));        // 12.8 MB
    int2*  recs2   = (int2*) alloc((size_t)N_EDGES_C * sizeof(int2));        // 12.8 MB

    const int EB = (N_EDGES_C + 255) / 256;       // 6250 edge blocks
    const int HB = (N_NODES_C * 8 + 255) / 256;   // 3125 hop blocks

    // --- CSR build (colored, low-amplification) ---
    hipMemsetAsync(cnt8, 0, (size_t)NCNT * sizeof(int), stream);
    hist8_kernel<<<EB, 256, 0, stream>>>(dst, cnt8);
    scan12k_kernel<<<1, 256, 0, stream>>>(cnt8, boff8, cur8);
    cfill_kernel<<<EB, 256, 0, stream>>>(src, dst, w, boff8, cur8, recs);
    sort_kernel<<<NB, 256, 0, stream>>>(recs, boff8, recs2, nodeoff);

    // --- h0 = relu(x W^T + b) ---
    linear_relu_kernel<<<(N_NODES_C + 255) / 256, 256, 0, stream>>>(
        x, W, b, h0, N_NODES_C);

    // --- 3 register-accumulating pull hops: h0 -> out -> h0 -> out ---
    hop_csr_kernel<<<HB, 256, 0, stream>>>(h0, nodeoff, recs2, out);
    hop_csr_kernel<<<HB, 256, 0, stream>>>(out, nodeoff, recs2, h0);
    hop_csr_kernel<<<HB, 256, 0, stream>>>(h0, nodeoff, recs2, out);
}

// Round 13
// 413.739 us; speedup vs baseline: 3.7055x; 1.0614x over previous
//
#include <hip/hip_runtime.h>

// SGC: h = relu(x @ W^T + b); 3x { h = segment_sum(h[src]*w, dst) }
// Round 13. Measured round-12: 439us total; linear_relu 83us (uncoalesced
// row-per-thread x reads), cfill 82us / WRITE 65MB (read-stream thrashes
// write-accumulation lines in L2). Fixes:
//  - linear: LDS-staged 64x128 tile, coalesced loads, wave-per-emb-group,
//    scalar W loads via readfirstlane.
//  - cfill: nontemporal loads for src/dst/w so streamed reads don't evict
//    partially-filled recs lines from L2 (write-amp 5x -> ~1x predicted).
// Hops (register-accumulating CSR pull) unchanged: measured good (~78us).
constexpr int N_NODES_C = 100000;
constexpr int N_EDGES_C = 1600000;
constexpr int IN_DIM_C  = 128;
constexpr int EMB       = 32;

constexpr int NPB   = 64;                            // nodes per bucket
constexpr int NB    = (N_NODES_C + NPB - 1) / NPB;   // 1563 buckets
constexpr int NCOL  = 8;                             // colors (XCD proxy)
constexpr int NCNT  = NB * NCOL;                     // 12504 counters
constexpr int SCAN_PER = (NCNT + 255) / 256;         // 49 per scan thread

constexpr int RPB = 64;    // rows per block (linear)
constexpr int XS  = 129;   // padded x-tile row stride in floats

// ---------------------------------------------------------------------------
// h0 = relu(x W^T + b), LDS-staged.
// 256 threads / 64 rows. Phase 1: coalesced load of x[64][128] into LDS
// (2048 float4s, thread t loads t, t+256, ...). Phase 2: wave w (= t>>6)
// computes emb group [w*8, w*8+8) for row (t&63); W/b via wave-uniform
// scalar loads (readfirstlane); x row from LDS (stride 129 -> 2-way, free).
// ---------------------------------------------------------------------------
__global__ __launch_bounds__(256) void linear_relu_lds_kernel(
    const float* __restrict__ x, const float* __restrict__ W,
    const float* __restrict__ b, float* __restrict__ h)
{
    __shared__ float xs[RPB * XS];   // 33 KB
    int t = threadIdx.x;
    int rbase = blockIdx.x * RPB;

#pragma unroll
    for (int i = 0; i < 8; ++i) {
        int f  = t + i * 256;       // float4 index in tile
        int r  = f >> 5;            // row 0..63
        int c4 = f & 31;            // float4 col 0..31
        int row = rbase + r;
        float4 v = make_float4(0.f, 0.f, 0.f, 0.f);
        if (row < N_NODES_C)
            v = *reinterpret_cast<const float4*>(
                    x + (size_t)row * IN_DIM_C + c4 * 4);
        float* p = &xs[r * XS + c4 * 4];
        p[0] = v.x; p[1] = v.y; p[2] = v.z; p[3] = v.w;
    }
    __syncthreads();

    int lane = t & 63;
    int e0   = __builtin_amdgcn_readfirstlane((t >> 6) * 8);  // wave-uniform
    int row  = rbase + lane;

    float acc[8];
#pragma unroll
    for (int j = 0; j < 8; ++j) acc[j] = 0.f;

    const float4* __restrict__ W4 = reinterpret_cast<const float4*>(W);
#pragma unroll 4
    for (int k4 = 0; k4 < IN_DIM_C / 4; ++k4) {
        const float* xr = &xs[lane * XS + k4 * 4];
        float xv0 = xr[0], xv1 = xr[1], xv2 = xr[2], xv3 = xr[3];
#pragma unroll
        for (int j = 0; j < 8; ++j) {
            float4 wv = W4[(e0 + j) * (IN_DIM_C / 4) + k4];  // s_load (K$)
            acc[j] = fmaf(xv0, wv.x,
                     fmaf(xv1, wv.y,
                     fmaf(xv2, wv.z,
                     fmaf(xv3, wv.w, acc[j]))));
        }
    }

    if (row < N_NODES_C) {
        float* outp = h + (size_t)row * EMB + e0;
#pragma unroll
        for (int j = 0; j < 8; ++j) {
            float v = acc[j] + b[e0 + j];
            outp[j] = v > 0.f ? v : 0.f;
        }
    }
}

// ---------------------------------------------------------------------------
// Hist over (bucket,color): cnt8[(dst>>6)*8 + (blockIdx&7)]++.
// ---------------------------------------------------------------------------
__global__ __launch_bounds__(256) void hist8_kernel(
    const int* __restrict__ dst, int* __restrict__ cnt8)
{
    int e = blockIdx.x * 256 + threadIdx.x;
    if (e < N_EDGES_C)
        atomicAdd(&cnt8[(dst[e] >> 6) * NCOL + (blockIdx.x & 7)], 1);
}

// ---------------------------------------------------------------------------
// Single-WG exclusive scan of 12504 counters -> boff8; zero cur8.
// ---------------------------------------------------------------------------
__global__ __launch_bounds__(256) void scan12k_kernel(
    const int* __restrict__ cnt8, int* __restrict__ boff8, int* __restrict__ cur8)
{
    int t = threadIdx.x;
    int base = t * SCAN_PER;
    int v[SCAN_PER];
    int s = 0;
#pragma unroll
    for (int i = 0; i < SCAN_PER; ++i) {
        int x = (base + i < NCNT) ? cnt8[base + i] : 0;
        v[i] = x; s += x;
    }
    int lane = t & 63, wid = t >> 6;
    int inc = s;
#pragma unroll
    for (int o = 1; o < 64; o <<= 1) {
        int u = __shfl_up(inc, o, 64);
        if (lane >= o) inc += u;
    }
    __shared__ int wtot[4];
    if (lane == 63) wtot[wid] = inc;
    __syncthreads();
    int wbase = 0;
    for (int i = 0; i < wid; ++i) wbase += wtot[i];
    int run = wbase + inc - s;
#pragma unroll
    for (int i = 0; i < SCAN_PER; ++i) {
        if (base + i < NCNT) { boff8[base + i] = run; cur8[base + i] = 0; }
        run += v[i];
    }
    if (t == 255) boff8[NCNT] = run;   // == N_EDGES_C
}

// ---------------------------------------------------------------------------
// Colored fill with NONTEMPORAL reads: streamed src/dst/w must not evict the
// partially-written recs lines from L2 (round-12: 65MB writes = 5x amp).
// ---------------------------------------------------------------------------
__global__ __launch_bounds__(256) void cfill_kernel(
    const int* __restrict__ src, const int* __restrict__ dst,
    const float* __restrict__ w, const int* __restrict__ boff8,
    int* __restrict__ cur8, int2* __restrict__ recs)
{
    int e = blockIdx.x * 256 + threadIdx.x;
    if (e >= N_EDGES_C) return;
    int   d  = __builtin_nontemporal_load(&dst[e]);
    int   s  = __builtin_nontemporal_load(&src[e]);
    float wt = __builtin_nontemporal_load(&w[e]);
    int idx = (d >> 6) * NCOL + (blockIdx.x & 7);
    int pos = boff8[idx] + atomicAdd(&cur8[idx], 1);
    recs[pos] = make_int2(s | ((d & 63) << 17), __float_as_int(wt));
}

// ---------------------------------------------------------------------------
// Per-bucket counting sort by dlow -> recs2 (node-contiguous) + nodeoff.
// recs is L2-resident (just written) -> normal loads.
// ---------------------------------------------------------------------------
__global__ __launch_bounds__(256) void sort_kernel(
    const int2* __restrict__ recs, const int* __restrict__ boff8,
    int2* __restrict__ recs2, int* __restrict__ nodeoff)
{
    __shared__ int hist[NPB];
    __shared__ int pfx[NPB];
    __shared__ int cur[NPB];
    int t = threadIdx.x;
    int b = blockIdx.x;
    if (t < NPB) { hist[t] = 0; cur[t] = 0; }
    __syncthreads();

    int beg = boff8[b * NCOL];
    int end = boff8[(b + 1) * NCOL];

    for (int j = beg + t; j < end; j += 256)
        atomicAdd(&hist[(recs[j].x >> 17) & 63], 1);
    __syncthreads();

    if (t == 0) {
        int run = 0;
        for (int i = 0; i < NPB; ++i) { pfx[i] = run; run += hist[i]; }
    }
    __syncthreads();

    if (t < NPB) {
        int node = b * NPB + t;
        if (node <= N_NODES_C) nodeoff[node] = beg + pfx[t];
    }

    for (int j = beg + t; j < end; j += 256) {
        int2 r = recs[j];
        int dlow = (r.x >> 17) & 63;
        int pos  = beg + pfx[dlow] + atomicAdd(&cur[dlow], 1);
        recs2[pos] = make_int2(r.x & 0x1FFFF, r.y);
    }
}

// ---------------------------------------------------------------------------
// Hop (pull, register accumulation): 8 lanes per node, one float4 per lane.
// Unroll-4 for memory-level parallelism. No atomics anywhere.
// ---------------------------------------------------------------------------
__global__ __launch_bounds__(256) void hop_csr_kernel(
    const float* __restrict__ h_in, const int* __restrict__ nodeoff,
    const int2* __restrict__ recs2, float* __restrict__ h_out)
{
    int tid = blockIdx.x * 256 + threadIdx.x;
    int node = tid >> 3;
    int q    = tid & 7;
    if (node >= N_NODES_C) return;

    int beg = nodeoff[node], end = nodeoff[node + 1];
    float4 acc = make_float4(0.f, 0.f, 0.f, 0.f);
    int j = beg;
    for (; j + 4 <= end; j += 4) {
        int2 ep0 = recs2[j + 0];
        int2 ep1 = recs2[j + 1];
        int2 ep2 = recs2[j + 2];
        int2 ep3 = recs2[j + 3];
        float4 h0 = *reinterpret_cast<const float4*>(h_in + (size_t)ep0.x * EMB + q * 4);
        float4 h1 = *reinterpret_cast<const float4*>(h_in + (size_t)ep1.x * EMB + q * 4);
        float4 h2 = *reinterpret_cast<const float4*>(h_in + (size_t)ep2.x * EMB + q * 4);
        float4 h3 = *reinterpret_cast<const float4*>(h_in + (size_t)ep3.x * EMB + q * 4);
        float w0 = __int_as_float(ep0.y), w1 = __int_as_float(ep1.y);
        float w2 = __int_as_float(ep2.y), w3 = __int_as_float(ep3.y);
        acc.x = fmaf(h0.x, w0, acc.x); acc.y = fmaf(h0.y, w0, acc.y);
        acc.z = fmaf(h0.z, w0, acc.z); acc.w = fmaf(h0.w, w0, acc.w);
        acc.x = fmaf(h1.x, w1, acc.x); acc.y = fmaf(h1.y, w1, acc.y);
        acc.z = fmaf(h1.z, w1, acc.z); acc.w = fmaf(h1.w, w1, acc.w);
        acc.x = fmaf(h2.x, w2, acc.x); acc.y = fmaf(h2.y, w2, acc.y);
        acc.z = fmaf(h2.z, w2, acc.z); acc.w = fmaf(h2.w, w2, acc.w);
        acc.x = fmaf(h3.x, w3, acc.x); acc.y = fmaf(h3.y, w3, acc.y);
        acc.z = fmaf(h3.z, w3, acc.z); acc.w = fmaf(h3.w, w3, acc.w);
    }
    for (; j < end; ++j) {
        int2  ep = recs2[j];
        float wt = __int_as_float(ep.y);
        float4 hv = *reinterpret_cast<const float4*>(h_in + (size_t)ep.x * EMB + q * 4);
        acc.x = fmaf(hv.x, wt, acc.x);
        acc.y = fmaf(hv.y, wt, acc.y);
        acc.z = fmaf(hv.z, wt, acc.z);
        acc.w = fmaf(hv.w, wt, acc.w);
    }
    *reinterpret_cast<float4*>(h_out + (size_t)node * EMB + q * 4) = acc;
}

extern "C" void kernel_launch(void* const* d_in, const int* in_sizes, int n_in,
                              void* d_out, int out_size, void* d_ws, size_t ws_size,
                              hipStream_t stream) {
    const float* x   = (const float*)d_in[0];
    const float* W   = (const float*)d_in[1];
    const float* b   = (const float*)d_in[2];
    const float* w   = (const float*)d_in[3];
    const int*   src = (const int*)d_in[4];
    const int*   dst = (const int*)d_in[5];
    // d_in[6] is k (== 3, fixed by setup); hardcoded.

    float* out = (float*)d_out;

    char* ws = (char*)d_ws;
    size_t o = 0;
    auto alloc = [&](size_t bytes) {
        char* p = ws + o;
        o += (bytes + 255) & ~(size_t)255;
        return p;
    };
    float* h0      = (float*)alloc((size_t)N_NODES_C * EMB * sizeof(float)); // 12.8 MB
    int*   cnt8    = (int*)  alloc((size_t)NCNT * sizeof(int));              // 50 KB
    int*   boff8   = (int*)  alloc((size_t)(NCNT + 1) * sizeof(int));        // 50 KB
    int*   cur8    = (int*)  alloc((size_t)NCNT * sizeof(int));              // 50 KB
    int*   nodeoff = (int*)  alloc((size_t)(N_NODES_C + 1) * sizeof(int));   // 400 KB
    int2*  recs    = (int2*) alloc((size_t)N_EDGES_C * sizeof(int2));        // 12.8 MB
    int2*  recs2   = (int2*) alloc((size_t)N_EDGES_C * sizeof(int2));        // 12.8 MB

    const int EB = (N_EDGES_C + 255) / 256;       // 6250 edge blocks
    const int HB = (N_NODES_C * 8 + 255) / 256;   // 3125 hop blocks
    const int LB = (N_NODES_C + RPB - 1) / RPB;   // 1563 linear blocks

    // --- CSR build (colored, low-amplification) ---
    hipMemsetAsync(cnt8, 0, (size_t)NCNT * sizeof(int), stream);
    hist8_kernel<<<EB, 256, 0, stream>>>(dst, cnt8);
    scan12k_kernel<<<1, 256, 0, stream>>>(cnt8, boff8, cur8);
    cfill_kernel<<<EB, 256, 0, stream>>>(src, dst, w, boff8, cur8, recs);
    sort_kernel<<<NB, 256, 0, stream>>>(recs, boff8, recs2, nodeoff);

    // --- h0 = relu(x W^T + b), LDS-staged coalesced ---
    linear_relu_lds_kernel<<<LB, 256, 0, stream>>>(x, W, b, h0);

    // --- 3 register-accumulating pull hops: h0 -> out -> h0 -> out ---
    hop_csr_kernel<<<HB, 256, 0, stream>>>(h0, nodeoff, recs2, out);
    hop_csr_kernel<<<HB, 256, 0, stream>>>(out, nodeoff, recs2, h0);
    hop_csr_kernel<<<HB, 256, 0, stream>>>(h0, nodeoff, recs2, out);
}